// Round 16
// baseline (191.039 us; speedup 1.0000x reference)
//
#include <hip/hip_runtime.h>

#define M_ROWS 12608          // 64*197
#define K_DIM  768
// Xc: 64 panels x 24 kt x 16 chunks x 512 shorts (chunk = [lane64][k8]) = 25.2 MB
#define XC_ELEMS (64*24*16*512)
// Wc: 12 heads x 24 kt x 12 chunks x 512 shorts = 3.5 MB
#define WC_ELEMS (12*24*12*512)

typedef __bf16 bf16x8 __attribute__((ext_vector_type(8)));
typedef float  f32x4  __attribute__((ext_vector_type(4)));

__device__ __forceinline__ unsigned short f2bf(float f) {
    unsigned u = __builtin_bit_cast(unsigned, f);
    u += 0x7fffu + ((u >> 16) & 1u);          // RNE, inputs are finite
    return (unsigned short)(u >> 16);
}

__device__ __forceinline__ void gll16(const unsigned short* g, unsigned short* l) {
    __builtin_amdgcn_global_load_lds(
        (const __attribute__((address_space(1))) unsigned int*)g,
        (__attribute__((address_space(3))) unsigned int*)l, 16, 0, 0);
}

// ---------------- Kernel 0: prep — emit X and W in GEMM-staging chunk order -----------
// (R15-verified: X-part LDS-staged, both global sides coalesced; ~BW floor.)
__global__ __launch_bounds__(256) void prep_kernel(
        const float* __restrict__ X, unsigned short* __restrict__ Xc,
        const float* __restrict__ W, unsigned short* __restrict__ Wc) {
    __shared__ __align__(16) unsigned short Lp[64 * 200];   // 25.6 KB
    __shared__ float tile[32][33];
    const int bid = blockIdx.x;
    const int t = threadIdx.x;
    if (bid < 1024) {
        const int p = bid >> 4, sub = bid & 15;
        const int rg = sub >> 2, kq = sub & 3;          // k-quarter: kt kq*6..kq*6+5
        const int w = t >> 6, lane = t & 63;

        // phase 1: read 64 x 192 floats coalesced, convert, stage to LDS
#pragma unroll
        for (int i = 0; i < 12; ++i) {
            const int f4 = i * 256 + t;                 // 0..3071 float4 units
            const int row = f4 / 48;                    // 48 float4 per row
            const int col4 = f4 - row * 48;
            const size_t grow = (size_t)p * 197 + rg * 64 + row;
            float4 v = (float4){0.f, 0.f, 0.f, 0.f};
            if (grow < M_ROWS)
                v = *(const float4*)(X + grow * K_DIM + kq * 192 + col4 * 4);
            ushort4 s;
            s.x = f2bf(v.x); s.y = f2bf(v.y); s.z = f2bf(v.z); s.w = f2bf(v.w);
            *(ushort4*)&Lp[row * 200 + col4 * 4] = s;
        }
        __syncthreads();

        // phase 2: 24 chunks; wave w writes chunks w*6..w*6+5
#pragma unroll
        for (int s = 0; s < 6; ++s) {
            const int cc = w * 6 + s;                   // 0..23
            const int ktl = cc >> 2, kc = cc & 3;
            const int kt = kq * 6 + ktl;
            bf16x8 v = *(const bf16x8*)&Lp[lane * 200 + ktl * 32 + kc * 8];
            *(bf16x8*)(Xc + ((size_t)p * 384 + kt * 16 + kc * 4 + rg) * 512 + lane * 8) = v;
        }
        return;
    }
    const int b2 = bid - 1024;
    const int n0 = (b2 % 72) * 32, k0 = (b2 / 72) * 32;
    const int tx = t & 31, ty = t >> 5;
#pragma unroll
    for (int i = 0; i < 4; ++i)
        tile[ty + i * 8][tx] = W[(size_t)(k0 + ty + i * 8) * 2304 + n0 + tx];   // [klocal][nlocal]
    __syncthreads();
    if (t < 128) {
        const int kc = t >> 5, tx2 = t & 31;
        const int grp = n0 / 768, remn = n0 - grp * 768;
        const int h = remn >> 6, lh = remn & 63;    // 0 or 32
        const int kt = k0 >> 5;
        uint4 u;
        u.x = f2bf(tile[kc * 8 + 0][tx2]) | ((unsigned)f2bf(tile[kc * 8 + 1][tx2]) << 16);
        u.y = f2bf(tile[kc * 8 + 2][tx2]) | ((unsigned)f2bf(tile[kc * 8 + 3][tx2]) << 16);
        u.z = f2bf(tile[kc * 8 + 4][tx2]) | ((unsigned)f2bf(tile[kc * 8 + 5][tx2]) << 16);
        u.w = f2bf(tile[kc * 8 + 6][tx2]) | ((unsigned)f2bf(tile[kc * 8 + 7][tx2]) << 16);
        *(uint4*)(Wc + (size_t)(((h * 24 + kt) * 12) + kc * 3 + grp) * 512 + (lh + tx2) * 8) = u;
    }
}

// ---------------- Kernel 1: FUSED per-head QKV-GEMM + attention, 3-ring staging -------
// R11/R15 kernel (95.6us) with ONE change: the K-loop's 2-buffer stage+vmcnt(0) drain
// becomes a 3-deep ring with COUNTED vmcnt (R2's recipe, now free: LDS total is set by
// the 136.6KB attn image, and 3-buf staging (86KB) aliases inside it; occupancy
// unchanged at 1 block/CU). Per iter kt: issue stage(kt+2) into buf[(kt+2)%3]
// (guarded kt+2<24 so no DMA outlives the loop); compute buf[kt%3]; bottom wait
// vmcnt(nst) = tile kt+1 landed, tile kt+2's loads STAY IN FLIGHT across the barrier
// (~2-iteration latency window vs 0 before). kt>=22 drains to 0.
// Ring safety: buf[(kt+2)%3] last read at iter kt-1 (barrier-separated); FIFO wait at
// bottom of kt+1 guarantees tile kt+2 landed before iter kt+2 reads it.
// LDS (shorts): staging A 3buf [0,24576) + B 3buf [24576,43008) DEAD after GEMM;
// attn image aliases: Qs [0,14184) | Ks [14184,28368) | Vt [28368,42192) |
// Ps [42192,68304). 136.6 KB, 1 block/CU.
__global__ __launch_bounds__(768) void fused_kernel(
        const unsigned short* __restrict__ Xc, const unsigned short* __restrict__ Wc,
        const float* __restrict__ bias, float* __restrict__ out) {
    __shared__ __align__(16) unsigned short L[68304];   // 136608 B

    const int t = threadIdx.x;
    const int w = t >> 6, lane = t & 63, quad = lane >> 4, l16 = lane & 15;
    const int wm = w / 3, wnn = w - wm * 3;     // 4M x 3N wave grid
    const int wrow0 = wm * 64;                  // GEMM rows owned
    const int wcol0 = wnn * 64;                 // GEMM cols owned

    // XCD-chunked bijective swizzle (768 = 8*96): each batch's 12 heads on one XCD
    const int lin = blockIdx.x;
    const int wg = (lin & 7) * 96 + (lin >> 3);
    const int bb = wg / 12, h = wg - bb * 12;

    // staging chunk table: chunks 0..15 = A (LDS base c*512, 3-buf stride 8192),
    // 16..27 = B (LDS base 24576+cb*512, 3-buf stride 6144). Wave w stages
    // {w, w+12, 24+w if w<4}; every chunk covered exactly once.
    const unsigned short* sgp[3];
    int sof[3], gst[3], bst[3];
    const int nst = (w < 4) ? 3 : 2;
    {
        const int clist[3] = {w, w + 12, 24 + w};
#pragma unroll
        for (int s = 0; s < 3; ++s) {
            const int c = clist[s];
            if (c < 16) {
                sgp[s] = Xc + ((size_t)bb * 384 + c) * 512 + lane * 8;
                sof[s] = c * 512; gst[s] = 8192; bst[s] = 8192;
            } else {
                const int cb = c - 16;
                sgp[s] = Wc + ((size_t)h * 288 + cb) * 512 + lane * 8;
                sof[s] = 24576 + cb * 512; gst[s] = 6144; bst[s] = 6144;
            }
        }
    }

    f32x4 acc[4][4];
#pragma unroll
    for (int i = 0; i < 4; ++i)
#pragma unroll
        for (int j = 0; j < 4; ++j) acc[i][j] = (f32x4){0.f, 0.f, 0.f, 0.f};

    // prologue: stage tiles 0,1 into bufs 0,1; land tile 0, keep tile 1 in flight
#pragma unroll
    for (int p = 0; p < 2; ++p)
#pragma unroll
        for (int s = 0; s < 3; ++s)
            if (s < nst) gll16(sgp[s] + (size_t)p * gst[s], &L[sof[s] + p * bst[s]]);
    if (w < 4) asm volatile("s_waitcnt vmcnt(3)" ::: "memory");
    else       asm volatile("s_waitcnt vmcnt(2)" ::: "memory");
    __builtin_amdgcn_s_barrier();
    asm volatile("" ::: "memory");

#pragma unroll 3
    for (int kt = 0; kt < 24; ++kt) {
        const int cur = kt % 3, stb = (kt + 2) % 3;

        // issue stage(kt+2) into ring slot; stays in flight across this iter's barrier
        if (kt + 2 < 24) {
#pragma unroll
            for (int s = 0; s < 3; ++s)
                if (s < nst) gll16(sgp[s] + (size_t)(kt + 2) * gst[s], &L[sof[s] + stb * bst[s]]);
        }

        const unsigned short* Ab = &L[cur * 8192];
        const unsigned short* Bb = &L[24576 + cur * 6144];
        bf16x8 af[4], bq[4];
#pragma unroll
        for (int i = 0; i < 4; ++i)
            af[i] = *(const bf16x8*)&Ab[quad * 2048 + (wrow0 + i * 16 + l16) * 8];
#pragma unroll
        for (int j = 0; j < 4; ++j)
            bq[j] = *(const bf16x8*)&Bb[quad * 1536 + (wcol0 + j * 16 + l16) * 8];

#pragma unroll
        for (int i = 0; i < 4; ++i)
#pragma unroll
            for (int j = 0; j < 4; ++j)
                acc[i][j] = __builtin_amdgcn_mfma_f32_16x16x32_bf16(af[i], bq[j], acc[i][j], 0, 0, 0);

        // counted checkpoint: tile kt+1 landed; tile kt+2's loads remain in flight
        if (kt < 22) {
            if (w < 4) asm volatile("s_waitcnt vmcnt(3)" ::: "memory");
            else       asm volatile("s_waitcnt vmcnt(2)" ::: "memory");
        } else {
            asm volatile("s_waitcnt vmcnt(0)" ::: "memory");
        }
        __builtin_amdgcn_s_barrier();
        asm volatile("" ::: "memory");
    }

    unsigned short* Qs = &L[0];       // [197][72]
    unsigned short* Ks = &L[14184];   // [197][72]
    unsigned short* Vt = &L[28368];   // [64][216] transposed
    unsigned short* Ps = &L[42192];   // 12 x 16 x 136

    // epilogue: bias, q-scale, scatter to Qs/Ks/Vt. which == wnn is WAVE-UNIFORM.
    // All DMA drained (vmcnt(0) at kt=22/23), all reads done (final barrier).
    {
        const float bscale = (wnn == 0) ? 0.125f : 1.0f;
#pragma unroll
        for (int j = 0; j < 4; ++j) {
            const int d = j * 16 + l16;             // 0..63
            const float bv = bias[wnn * 768 + h * 64 + d];
#pragma unroll
            for (int i = 0; i < 4; ++i) {
                const int rowb = wrow0 + i * 16 + quad * 4;
#pragma unroll
                for (int r = 0; r < 4; ++r) {
                    const int row = rowb + r;
                    if (row >= 197) continue;
                    const float val = (acc[i][j][r] + bv) * bscale;
                    if (wnn == 0)      Qs[row * 72 + d] = f2bf(val);
                    else if (wnn == 1) Ks[row * 72 + d] = f2bf(val);
                    else               Vt[d * 216 + row] = f2bf(val);
                }
            }
        }
    }
    // zero Vt pad cols 197..215 (PV reads them where p==0; avoid NaN*0)
    for (int idx = t; idx < 64 * 19; idx += 768) {
        int d = idx / 19, c = 197 + idx - d * 19;
        Vt[d * 216 + c] = 0;
    }
    __syncthreads();

    // ---------------- attention phase (proven structure; Q/K/V already in LDS) --------
    unsigned short* Pw = Ps + w * (16 * 136);

    for (int tile = w; tile < 13; tile += 12) {
        int rq = tile * 16 + l16;
        int tokq = rq < 197 ? rq : 196;
        bf16x8 aq0 = *(const bf16x8*)&Qs[tokq * 72 + quad * 8];
        bf16x8 aq1 = *(const bf16x8*)&Qs[tokq * 72 + 32 + quad * 8];

        // scores: 13 chunks of 16 kt-cols, K fragments from LDS
        f32x4 s[13];
        __builtin_amdgcn_s_setprio(1);
#pragma unroll
        for (int c = 0; c < 13; ++c) {
            int krow = c * 16 + l16;
            if (krow > 196) krow = 196;             // clamped read; masked below
            bf16x8 kb0 = *(const bf16x8*)&Ks[krow * 72 + quad * 8];
            bf16x8 kb1 = *(const bf16x8*)&Ks[krow * 72 + 32 + quad * 8];
            f32x4 zz = (f32x4){0.f, 0.f, 0.f, 0.f};
            zz = __builtin_amdgcn_mfma_f32_16x16x32_bf16(aq0, kb0, zz, 0, 0, 0);
            zz = __builtin_amdgcn_mfma_f32_16x16x32_bf16(aq1, kb1, zz, 0, 0, 0);
            s[c] = zz;
        }
        __builtin_amdgcn_s_setprio(0);
        if (l16 >= 5) { s[12][0] = -1e30f; s[12][1] = -1e30f; s[12][2] = -1e30f; s[12][3] = -1e30f; }

        // softmax over 208 cols (rows = quad*4+r, cols spread over l16)
        float mx[4], lsum[4];
#pragma unroll
        for (int r = 0; r < 4; ++r) {
            float m = s[0][r];
#pragma unroll
            for (int c = 1; c < 13; ++c) m = fmaxf(m, s[c][r]);
#pragma unroll
            for (int d = 1; d < 16; d <<= 1) m = fmaxf(m, __shfl_xor(m, d));
            mx[r] = m;
            lsum[r] = 0.f;
        }
#pragma unroll
        for (int c = 0; c < 13; ++c)
#pragma unroll
            for (int r = 0; r < 4; ++r) {
                float p = __expf(s[c][r] - mx[r]);
                s[c][r] = p;
                lsum[r] += p;
            }
#pragma unroll
        for (int r = 0; r < 4; ++r)
#pragma unroll
            for (int d = 1; d < 16; d <<= 1) lsum[r] += __shfl_xor(lsum[r], d);

        f32x4 o[4];
#pragma unroll
        for (int j = 0; j < 4; ++j) o[j] = (f32x4){0.f, 0.f, 0.f, 0.f};

        // PV pass 1: P cols 0..127 (same-wave LDS round trip, no barrier)
#pragma unroll
        for (int c = 0; c < 8; ++c)
#pragma unroll
            for (int r = 0; r < 4; ++r)
                Pw[(quad * 4 + r) * 136 + c * 16 + l16] = f2bf(s[c][r]);
        __builtin_amdgcn_s_setprio(1);
#pragma unroll
        for (int kc = 0; kc < 4; ++kc) {
            int kof = kc * 32 + quad * 8;
            bf16x8 ap = *(const bf16x8*)&Pw[l16 * 136 + kof];
#pragma unroll
            for (int j = 0; j < 4; ++j) {
                bf16x8 bv = *(const bf16x8*)&Vt[(j * 16 + l16) * 216 + kof];
                o[j] = __builtin_amdgcn_mfma_f32_16x16x32_bf16(ap, bv, o[j], 0, 0, 0);
            }
        }
        __builtin_amdgcn_s_setprio(0);
        // PV pass 2: P cols 128..207 -> buffer cols 0..79; cols 80..95 zeroed (p==0)
#pragma unroll
        for (int r = 0; r < 4; ++r)
            Pw[(quad * 4 + r) * 136 + 80 + l16] = 0;
#pragma unroll
        for (int c = 8; c < 13; ++c)
#pragma unroll
            for (int r = 0; r < 4; ++r)
                Pw[(quad * 4 + r) * 136 + (c - 8) * 16 + l16] = f2bf(s[c][r]);
        __builtin_amdgcn_s_setprio(1);
#pragma unroll
        for (int kc = 0; kc < 3; ++kc) {
            int kofA = kc * 32 + quad * 8;
            // kc==2, quad>=2 -> kt 208..223 where p==0 exactly; clamp LDS read in-range
            int kofB = (kc == 2 && quad >= 2) ? 0 : kofA;
            bf16x8 ap = *(const bf16x8*)&Pw[l16 * 136 + kofA];
#pragma unroll
            for (int j = 0; j < 4; ++j) {
                bf16x8 bv = *(const bf16x8*)&Vt[(j * 16 + l16) * 216 + 128 + kofB];
                o[j] = __builtin_amdgcn_mfma_f32_16x16x32_bf16(ap, bv, o[j], 0, 0, 0);
            }
        }
        __builtin_amdgcn_s_setprio(0);

        // epilogue: divide by l, store fp32 [B, tok, 768]
        int tokbase = tile * 16 + quad * 4;
#pragma unroll
        for (int r = 0; r < 4; ++r) {
            int tr = tokbase + r;
            if (tr >= 197) continue;
            float inv = 1.f / lsum[r];
#pragma unroll
            for (int j = 0; j < 4; ++j)
                out[((size_t)(bb * 197 + tr)) * 768 + h * 64 + j * 16 + l16] = o[j][r] * inv;
        }
    }
}

extern "C" void kernel_launch(void* const* d_in, const int* in_sizes, int n_in,
                              void* d_out, int out_size, void* d_ws, size_t ws_size,
                              hipStream_t stream) {
    const float* X    = (const float*)d_in[0];   // [64,197,768]
    const float* W    = (const float*)d_in[1];   // [768,2304]
    const float* bias = (const float*)d_in[2];   // [2304]
    float* out = (float*)d_out;                  // [64,197,768]

    // Xc and Wc (chunk-order staging images) live in d_ws
    unsigned short* Xc = (unsigned short*)d_ws;
    unsigned short* Wc = (unsigned short*)d_ws + XC_ELEMS;

    prep_kernel<<<2752, 256, 0, stream>>>(X, Xc, W, Wc);
    fused_kernel<<<768, 768, 0, stream>>>(Xc, Wc, bias, out);
}

// Round 17
// 185.133 us; speedup vs baseline: 1.0319x; 1.0319x over previous
//
#include <hip/hip_runtime.h>

#define M_ROWS 12608          // 64*197
#define K_DIM  768
// Xc: 64 panels x 24 kt x 16 chunks x 512 shorts (chunk = [lane64][k8]) = 25.2 MB
#define XC_ELEMS (64*24*16*512)
// Wc: 12 heads x 24 kt x 12 chunks x 512 shorts = 3.5 MB
#define WC_ELEMS (12*24*12*512)

typedef __bf16 bf16x8 __attribute__((ext_vector_type(8)));
typedef float  f32x4  __attribute__((ext_vector_type(4)));

__device__ __forceinline__ unsigned short f2bf(float f) {
    unsigned u = __builtin_bit_cast(unsigned, f);
    u += 0x7fffu + ((u >> 16) & 1u);          // RNE, inputs are finite
    return (unsigned short)(u >> 16);
}

__device__ __forceinline__ void gll16(const unsigned short* g, unsigned short* l) {
    __builtin_amdgcn_global_load_lds(
        (const __attribute__((address_space(1))) unsigned int*)g,
        (__attribute__((address_space(3))) unsigned int*)l, 16, 0, 0);
}

// ---------------- Kernel 0: prep — emit X and W in GEMM-staging chunk order -----------
// (R15-verified: X-part LDS-staged, both global sides coalesced; ~BW floor.)
__global__ __launch_bounds__(256) void prep_kernel(
        const float* __restrict__ X, unsigned short* __restrict__ Xc,
        const float* __restrict__ W, unsigned short* __restrict__ Wc) {
    __shared__ __align__(16) unsigned short Lp[64 * 200];   // 25.6 KB
    __shared__ float tile[32][33];
    const int bid = blockIdx.x;
    const int t = threadIdx.x;
    if (bid < 1024) {
        const int p = bid >> 4, sub = bid & 15;
        const int rg = sub >> 2, kq = sub & 3;          // k-quarter: kt kq*6..kq*6+5
        const int w = t >> 6, lane = t & 63;

        // phase 1: read 64 x 192 floats coalesced, convert, stage to LDS
#pragma unroll
        for (int i = 0; i < 12; ++i) {
            const int f4 = i * 256 + t;                 // 0..3071 float4 units
            const int row = f4 / 48;                    // 48 float4 per row
            const int col4 = f4 - row * 48;
            const size_t grow = (size_t)p * 197 + rg * 64 + row;
            float4 v = (float4){0.f, 0.f, 0.f, 0.f};
            if (grow < M_ROWS)
                v = *(const float4*)(X + grow * K_DIM + kq * 192 + col4 * 4);
            ushort4 s;
            s.x = f2bf(v.x); s.y = f2bf(v.y); s.z = f2bf(v.z); s.w = f2bf(v.w);
            *(ushort4*)&Lp[row * 200 + col4 * 4] = s;
        }
        __syncthreads();

        // phase 2: 24 chunks; wave w writes chunks w*6..w*6+5
#pragma unroll
        for (int s = 0; s < 6; ++s) {
            const int cc = w * 6 + s;                   // 0..23
            const int ktl = cc >> 2, kc = cc & 3;
            const int kt = kq * 6 + ktl;
            bf16x8 v = *(const bf16x8*)&Lp[lane * 200 + ktl * 32 + kc * 8];
            *(bf16x8*)(Xc + ((size_t)p * 384 + kt * 16 + kc * 4 + rg) * 512 + lane * 8) = v;
        }
        return;
    }
    const int b2 = bid - 1024;
    const int n0 = (b2 % 72) * 32, k0 = (b2 / 72) * 32;
    const int tx = t & 31, ty = t >> 5;
#pragma unroll
    for (int i = 0; i < 4; ++i)
        tile[ty + i * 8][tx] = W[(size_t)(k0 + ty + i * 8) * 2304 + n0 + tx];   // [klocal][nlocal]
    __syncthreads();
    if (t < 128) {
        const int kc = t >> 5, tx2 = t & 31;
        const int grp = n0 / 768, remn = n0 - grp * 768;
        const int h = remn >> 6, lh = remn & 63;    // 0 or 32
        const int kt = k0 >> 5;
        uint4 u;
        u.x = f2bf(tile[kc * 8 + 0][tx2]) | ((unsigned)f2bf(tile[kc * 8 + 1][tx2]) << 16);
        u.y = f2bf(tile[kc * 8 + 2][tx2]) | ((unsigned)f2bf(tile[kc * 8 + 3][tx2]) << 16);
        u.z = f2bf(tile[kc * 8 + 4][tx2]) | ((unsigned)f2bf(tile[kc * 8 + 5][tx2]) << 16);
        u.w = f2bf(tile[kc * 8 + 6][tx2]) | ((unsigned)f2bf(tile[kc * 8 + 7][tx2]) << 16);
        *(uint4*)(Wc + (size_t)(((h * 24 + kt) * 12) + kc * 3 + grp) * 512 + (lh + tx2) * 8) = u;
    }
}

// ---------------- Kernel 1: FUSED per-head QKV-GEMM + attention, 12 waves -------------
// EXACT R15/R11 structure (best: fused 95.6us) with ONE cleanup: the kt=23 dummy
// restage (28KB dead DMA + drain, ~600-900cy/block) is removed — staging is guarded
// by kt<23. Final iteration has nothing in flight; trailing vmcnt(0) is a no-op and
// the attn-image aliasing safety is unchanged (all DMA landed by the final barrier).
// LDS (shorts): staging A dbuf [0,16384) + B dbuf [16384,28672) DEAD after GEMM;
// attn image aliases: Qs [0,14184) | Ks [14184,28368) | Vt [28368,42192) |
// Ps [42192,68304). 136.6 KB, 1 block/CU.
__global__ __launch_bounds__(768) void fused_kernel(
        const unsigned short* __restrict__ Xc, const unsigned short* __restrict__ Wc,
        const float* __restrict__ bias, float* __restrict__ out) {
    __shared__ __align__(16) unsigned short L[68304];   // 136608 B

    const int t = threadIdx.x;
    const int w = t >> 6, lane = t & 63, quad = lane >> 4, l16 = lane & 15;
    const int wm = w / 3, wnn = w - wm * 3;     // 4M x 3N wave grid
    const int wrow0 = wm * 64;                  // GEMM rows owned
    const int wcol0 = wnn * 64;                 // GEMM cols owned

    // XCD-chunked bijective swizzle (768 = 8*96): each batch's 12 heads on one XCD
    const int lin = blockIdx.x;
    const int wg = (lin & 7) * 96 + (lin >> 3);
    const int bb = wg / 12, h = wg - bb * 12;

    // staging chunk table: chunks 0..15 = A (offset c*512, kstep 8192, dbuf 8192),
    // 16..27 = B (offset 16384+cb*512, kstep 6144, dbuf 6144). Wave w stages
    // {w, w+12, 24+w if w<4}; every chunk covered exactly once.
    const unsigned short* sgp[3];
    int sof[3], gst[3], bst[3];
    const int nst = (w < 4) ? 3 : 2;
    {
        const int clist[3] = {w, w + 12, 24 + w};
#pragma unroll
        for (int s = 0; s < 3; ++s) {
            const int c = clist[s];
            if (c < 16) {
                sgp[s] = Xc + ((size_t)bb * 384 + c) * 512 + lane * 8;
                sof[s] = c * 512; gst[s] = 8192; bst[s] = 8192;
            } else {
                const int cb = c - 16;
                sgp[s] = Wc + ((size_t)h * 288 + cb) * 512 + lane * 8;
                sof[s] = 16384 + cb * 512; gst[s] = 6144; bst[s] = 6144;
            }
        }
    }

    f32x4 acc[4][4];
#pragma unroll
    for (int i = 0; i < 4; ++i)
#pragma unroll
        for (int j = 0; j < 4; ++j) acc[i][j] = (f32x4){0.f, 0.f, 0.f, 0.f};

    // prologue: stage tile 0 into buf 0, land it
#pragma unroll
    for (int s = 0; s < 3; ++s)
        if (s < nst) gll16(sgp[s], &L[sof[s]]);
    asm volatile("s_waitcnt vmcnt(0)" ::: "memory");
    __builtin_amdgcn_s_barrier();
    asm volatile("" ::: "memory");

#pragma unroll 2
    for (int kt = 0; kt < 24; ++kt) {
        const int cur = kt & 1, nxt = cur ^ 1;

        // issue next tile's staging first; body overlaps its latency (no dead tail)
        if (kt < 23) {
#pragma unroll
            for (int s = 0; s < 3; ++s)
                if (s < nst) gll16(sgp[s] + (size_t)(kt + 1) * gst[s], &L[sof[s] + nxt * bst[s]]);
        }

        const unsigned short* Ab = &L[cur * 8192];
        const unsigned short* Bb = &L[16384 + cur * 6144];
        bf16x8 af[4], bq[4];
#pragma unroll
        for (int i = 0; i < 4; ++i)
            af[i] = *(const bf16x8*)&Ab[quad * 2048 + (wrow0 + i * 16 + l16) * 8];
#pragma unroll
        for (int j = 0; j < 4; ++j)
            bq[j] = *(const bf16x8*)&Bb[quad * 1536 + (wcol0 + j * 16 + l16) * 8];

#pragma unroll
        for (int i = 0; i < 4; ++i)
#pragma unroll
            for (int j = 0; j < 4; ++j)
                acc[i][j] = __builtin_amdgcn_mfma_f32_16x16x32_bf16(af[i], bq[j], acc[i][j], 0, 0, 0);

        asm volatile("s_waitcnt vmcnt(0)" ::: "memory");
        __builtin_amdgcn_s_barrier();
        asm volatile("" ::: "memory");
    }

    unsigned short* Qs = &L[0];       // [197][72]
    unsigned short* Ks = &L[14184];   // [197][72]
    unsigned short* Vt = &L[28368];   // [64][216] transposed
    unsigned short* Ps = &L[42192];   // 12 x 16 x 136

    // epilogue: bias, q-scale, scatter to Qs/Ks/Vt. which == wnn is WAVE-UNIFORM.
    {
        const float bscale = (wnn == 0) ? 0.125f : 1.0f;
#pragma unroll
        for (int j = 0; j < 4; ++j) {
            const int d = j * 16 + l16;             // 0..63
            const float bv = bias[wnn * 768 + h * 64 + d];
#pragma unroll
            for (int i = 0; i < 4; ++i) {
                const int rowb = wrow0 + i * 16 + quad * 4;
#pragma unroll
                for (int r = 0; r < 4; ++r) {
                    const int row = rowb + r;
                    if (row >= 197) continue;
                    const float val = (acc[i][j][r] + bv) * bscale;
                    if (wnn == 0)      Qs[row * 72 + d] = f2bf(val);
                    else if (wnn == 1) Ks[row * 72 + d] = f2bf(val);
                    else               Vt[d * 216 + row] = f2bf(val);
                }
            }
        }
    }
    // zero Vt pad cols 197..215 (PV reads them where p==0; avoid NaN*0)
    for (int idx = t; idx < 64 * 19; idx += 768) {
        int d = idx / 19, c = 197 + idx - d * 19;
        Vt[d * 216 + c] = 0;
    }
    __syncthreads();

    // ---------------- attention phase (proven structure; Q/K/V already in LDS) --------
    unsigned short* Pw = Ps + w * (16 * 136);

    for (int tile = w; tile < 13; tile += 12) {
        int rq = tile * 16 + l16;
        int tokq = rq < 197 ? rq : 196;
        bf16x8 aq0 = *(const bf16x8*)&Qs[tokq * 72 + quad * 8];
        bf16x8 aq1 = *(const bf16x8*)&Qs[tokq * 72 + 32 + quad * 8];

        // scores: 13 chunks of 16 kt-cols, K fragments from LDS
        f32x4 s[13];
        __builtin_amdgcn_s_setprio(1);
#pragma unroll
        for (int c = 0; c < 13; ++c) {
            int krow = c * 16 + l16;
            if (krow > 196) krow = 196;             // clamped read; masked below
            bf16x8 kb0 = *(const bf16x8*)&Ks[krow * 72 + quad * 8];
            bf16x8 kb1 = *(const bf16x8*)&Ks[krow * 72 + 32 + quad * 8];
            f32x4 zz = (f32x4){0.f, 0.f, 0.f, 0.f};
            zz = __builtin_amdgcn_mfma_f32_16x16x32_bf16(aq0, kb0, zz, 0, 0, 0);
            zz = __builtin_amdgcn_mfma_f32_16x16x32_bf16(aq1, kb1, zz, 0, 0, 0);
            s[c] = zz;
        }
        __builtin_amdgcn_s_setprio(0);
        if (l16 >= 5) { s[12][0] = -1e30f; s[12][1] = -1e30f; s[12][2] = -1e30f; s[12][3] = -1e30f; }

        // softmax over 208 cols (rows = quad*4+r, cols spread over l16)
        float mx[4], lsum[4];
#pragma unroll
        for (int r = 0; r < 4; ++r) {
            float m = s[0][r];
#pragma unroll
            for (int c = 1; c < 13; ++c) m = fmaxf(m, s[c][r]);
#pragma unroll
            for (int d = 1; d < 16; d <<= 1) m = fmaxf(m, __shfl_xor(m, d));
            mx[r] = m;
            lsum[r] = 0.f;
        }
#pragma unroll
        for (int c = 0; c < 13; ++c)
#pragma unroll
            for (int r = 0; r < 4; ++r) {
                float p = __expf(s[c][r] - mx[r]);
                s[c][r] = p;
                lsum[r] += p;
            }
#pragma unroll
        for (int r = 0; r < 4; ++r)
#pragma unroll
            for (int d = 1; d < 16; d <<= 1) lsum[r] += __shfl_xor(lsum[r], d);

        f32x4 o[4];
#pragma unroll
        for (int j = 0; j < 4; ++j) o[j] = (f32x4){0.f, 0.f, 0.f, 0.f};

        // PV pass 1: P cols 0..127 (same-wave LDS round trip, no barrier)
#pragma unroll
        for (int c = 0; c < 8; ++c)
#pragma unroll
            for (int r = 0; r < 4; ++r)
                Pw[(quad * 4 + r) * 136 + c * 16 + l16] = f2bf(s[c][r]);
        __builtin_amdgcn_s_setprio(1);
#pragma unroll
        for (int kc = 0; kc < 4; ++kc) {
            int kof = kc * 32 + quad * 8;
            bf16x8 ap = *(const bf16x8*)&Pw[l16 * 136 + kof];
#pragma unroll
            for (int j = 0; j < 4; ++j) {
                bf16x8 bv = *(const bf16x8*)&Vt[(j * 16 + l16) * 216 + kof];
                o[j] = __builtin_amdgcn_mfma_f32_16x16x32_bf16(ap, bv, o[j], 0, 0, 0);
            }
        }
        __builtin_amdgcn_s_setprio(0);
        // PV pass 2: P cols 128..207 -> buffer cols 0..79; cols 80..95 zeroed (p==0)
#pragma unroll
        for (int r = 0; r < 4; ++r)
            Pw[(quad * 4 + r) * 136 + 80 + l16] = 0;
#pragma unroll
        for (int c = 8; c < 13; ++c)
#pragma unroll
            for (int r = 0; r < 4; ++r)
                Pw[(quad * 4 + r) * 136 + (c - 8) * 16 + l16] = f2bf(s[c][r]);
        __builtin_amdgcn_s_setprio(1);
#pragma unroll
        for (int kc = 0; kc < 3; ++kc) {
            int kofA = kc * 32 + quad * 8;
            // kc==2, quad>=2 -> kt 208..223 where p==0 exactly; clamp LDS read in-range
            int kofB = (kc == 2 && quad >= 2) ? 0 : kofA;
            bf16x8 ap = *(const bf16x8*)&Pw[l16 * 136 + kofA];
#pragma unroll
            for (int j = 0; j < 4; ++j) {
                bf16x8 bv = *(const bf16x8*)&Vt[(j * 16 + l16) * 216 + 128 + kofB];
                o[j] = __builtin_amdgcn_mfma_f32_16x16x32_bf16(ap, bv, o[j], 0, 0, 0);
            }
        }
        __builtin_amdgcn_s_setprio(0);

        // epilogue: divide by l, store fp32 [B, tok, 768]
        int tokbase = tile * 16 + quad * 4;
#pragma unroll
        for (int r = 0; r < 4; ++r) {
            int tr = tokbase + r;
            if (tr >= 197) continue;
            float inv = 1.f / lsum[r];
#pragma unroll
            for (int j = 0; j < 4; ++j)
                out[((size_t)(bb * 197 + tr)) * 768 + h * 64 + j * 16 + l16] = o[j][r] * inv;
        }
    }
}

extern "C" void kernel_launch(void* const* d_in, const int* in_sizes, int n_in,
                              void* d_out, int out_size, void* d_ws, size_t ws_size,
                              hipStream_t stream) {
    const float* X    = (const float*)d_in[0];   // [64,197,768]
    const float* W    = (const float*)d_in[1];   // [768,2304]
    const float* bias = (const float*)d_in[2];   // [2304]
    float* out = (float*)d_out;                  // [64,197,768]

    // Xc and Wc (chunk-order staging images) live in d_ws
    unsigned short* Xc = (unsigned short*)d_ws;
    unsigned short* Wc = (unsigned short*)d_ws + XC_ELEMS;

    prep_kernel<<<2752, 256, 0, stream>>>(X, Xc, W, Wc);
    fused_kernel<<<768, 768, 0, stream>>>(Xc, Wc, bias, out);
}